// Round 2
// baseline (339.503 us; speedup 1.0000x reference)
//
#include <hip/hip_runtime.h>

// MHA: B=2, S=4096, D=768, H=12, dk=64. Inputs/outputs fp32; compute bf16
// MFMA + fp32 accum. q = X wq^T + bq ; s = q k^T/8 ; p = softmax ; x = p v ;
// out = x wo^T + bo.
//
// R11: GEMM latency fix. At K=768 (12 K-steps) the old loop issued
// global_load_lds and drained it at the very next barrier -> every K-step
// paid full L2/L3 latency un-overlapped (~10% MFMA util). Now: double-
// buffered LDS (2x32KB, 2 blocks/CU) with next-tile gld16 issued BEFORE the
// current tile's ds_read+MFMA — loads stay in flight across the compute
// phase, drained by the following barrier (T3-minimum 2-phase, m248
// pattern). cvt kernels: grid-stride (~2K blocks) instead of 9216 tiny
// blocks (launch-rate-bound). attn unchanged from R10.

typedef __attribute__((ext_vector_type(8))) short short8;      // MFMA A/B frag
typedef __attribute__((ext_vector_type(8))) unsigned short ushort8;
typedef __attribute__((ext_vector_type(4))) unsigned short bf16x4;  // NOT ushort4 (HIP-reserved)
typedef __attribute__((ext_vector_type(4))) float f32x4;

// exp(s/8) = 2^(s * 0.125 * log2(e))
#define SCL 0.18033688011112042f

__device__ __forceinline__ unsigned short f2bf(float f) {
    unsigned int u = __builtin_bit_cast(unsigned int, f);
    u += 0x7fffu + ((u >> 16) & 1u);          // RNE
    return (unsigned short)(u >> 16);
}

// async global->LDS, 16B per lane; LDS dest must be lane-linear (base + lane*16)
__device__ __forceinline__ void gld16(const void* g, void* l) {
    __builtin_amdgcn_global_load_lds(
        (const __attribute__((address_space(1))) unsigned int*)g,
        (__attribute__((address_space(3))) unsigned int*)l, 16, 0, 0);
}

// load 8 contiguous elements as bf16x8 (converting if fp32)
__device__ __forceinline__ ushort8 ld8(const unsigned short* p) {
    return *(const ushort8*)p;
}
__device__ __forceinline__ ushort8 ld8(const float* p) {
    f32x4 a = *(const f32x4*)p;
    f32x4 b = *(const f32x4*)(p + 4);
    ushort8 r;
    r[0] = f2bf(a[0]); r[1] = f2bf(a[1]); r[2] = f2bf(a[2]); r[3] = f2bf(a[3]);
    r[4] = f2bf(b[0]); r[5] = f2bf(b[1]); r[6] = f2bf(b[2]); r[7] = f2bf(b[3]);
    return r;
}
__device__ __forceinline__ void st1(unsigned short* p, float v) { *p = f2bf(v); }
__device__ __forceinline__ void st1(float* p, float v)          { *p = v; }

// fp32 -> bf16 bulk convert; gridDim.y selects tensor (up to 4); grid-stride
__global__ __launch_bounds__(256) void cvt_bf16(
    const float* __restrict__ s0, unsigned short* __restrict__ d0,
    const float* __restrict__ s1, unsigned short* __restrict__ d1,
    const float* __restrict__ s2, unsigned short* __restrict__ d2,
    const float* __restrict__ s3, unsigned short* __restrict__ d3, int n)
{
    const float* s; unsigned short* d;
    if (blockIdx.y == 0)      { s = s0; d = d0; }
    else if (blockIdx.y == 1) { s = s1; d = d1; }
    else if (blockIdx.y == 2) { s = s2; d = d2; }
    else                      { s = s3; d = d3; }
    const int step = gridDim.x * 2048;            // 256 threads * 8 elems
    for (int i = (blockIdx.x * 256 + threadIdx.x) * 8; i + 8 <= n; i += step) {
        f32x4 a = *(const f32x4*)&s[i];
        f32x4 b = *(const f32x4*)&s[i + 4];
        ushort8 r;
        r[0] = f2bf(a[0]); r[1] = f2bf(a[1]); r[2] = f2bf(a[2]); r[3] = f2bf(a[3]);
        r[4] = f2bf(b[0]); r[5] = f2bf(b[1]); r[6] = f2bf(b[2]); r[7] = f2bf(b[3]);
        *(ushort8*)&d[i] = r;
    }
}

// ---------------------------------------------------------------------------
// GEMM: Y[M,N] = X[M,K] * W[N,K]^T + bias[N], fp32 accum, bf16 MFMA.
// 128x128 tile, BK=64, 4 waves x (64x64). blockIdx.z muxes 3 tuples.
// Double-buffered LDS + prefetch-issue-early: next tile's global_load_lds
// issued before current tile's ds_read/MFMA, so the vmcnt(0) drain at the
// next barrier finds the loads complete (latency hidden under compute).
// transZ2: tuple 2 writes Y transposed ([N][M], bf16 only) for V^T.
// ---------------------------------------------------------------------------
template<typename TX, typename TW, typename TY>
__global__ __launch_bounds__(256, 2) void gemm_bt(
    const TX* __restrict__ X0, const TW* __restrict__ W0,
    const float* __restrict__ B0, TY* __restrict__ Y0,
    const TX* __restrict__ X1, const TW* __restrict__ W1,
    const float* __restrict__ B1, TY* __restrict__ Y1,
    const TX* __restrict__ X2, const TW* __restrict__ W2,
    const float* __restrict__ B2, TY* __restrict__ Y2,
    int M, int N, int K, int transZ2)
{
    __shared__ __align__(16) unsigned short lds_a[2][128 * 64];  // 32 KB
    __shared__ __align__(16) unsigned short lds_b[2][128 * 64];  // 32 KB

    const TX *X; const TW *W; const float *Bi; TY *Y;
    if (blockIdx.z == 0)      { X = X0; W = W0; Bi = B0; Y = Y0; }
    else if (blockIdx.z == 1) { X = X1; W = W1; Bi = B1; Y = Y1; }
    else                      { X = X2; W = W2; Bi = B2; Y = Y2; }

    const int tid = threadIdx.x;
    const int wave = tid >> 6, lane = tid & 63;
    const int lane15 = lane & 15, quad = lane >> 4;
    const int m0 = blockIdx.x * 128, n0 = blockIdx.y * 128;
    const int wm = (wave & 1) * 64, wn = (wave >> 1) * 64;

    auto stage = [&](int buf, int k0) {
#pragma unroll
        for (int i = 0; i < 4; i++) {
            int c  = tid + 256 * i;            // 0..1023 chunks of 8 elems
            int r  = c >> 3;                   // 0..127
            int c8 = (c & 7) * 8;              // 0..56
            if constexpr (sizeof(TX) == 2 && sizeof(TW) == 2) {
                gld16(&X[(size_t)(m0 + r) * K + k0 + c8], &lds_a[buf][c * 8]);
                gld16(&W[(size_t)(n0 + r) * K + k0 + c8], &lds_b[buf][c * 8]);
            } else {
                *(ushort8*)&lds_a[buf][r * 64 + c8] = ld8(&X[(size_t)(m0 + r) * K + k0 + c8]);
                *(ushort8*)&lds_b[buf][r * 64 + c8] = ld8(&W[(size_t)(n0 + r) * K + k0 + c8]);
            }
        }
    };

    f32x4 acc[4][4] = {};
    const int NT = K >> 6;                     // 12 for K=768
    int cur = 0;

    stage(0, 0);                               // prologue: first tile

    for (int t = 0; t < NT; t++) {
        __syncthreads();                       // drains buf[cur] staging (vmcnt)
                                               // + prev iteration's LDS reads
        if (t + 1 < NT) stage(cur ^ 1, (t + 1) << 6);  // in flight over compute

        const unsigned short* la = lds_a[cur];
        const unsigned short* lb = lds_b[cur];

        short8 af[4][2], bfr[4][2];
#pragma unroll
        for (int mt = 0; mt < 4; mt++)
#pragma unroll
            for (int ks = 0; ks < 2; ks++)
                af[mt][ks] = *(const short8*)&la[(wm + mt * 16 + lane15) * 64
                                                 + ks * 32 + quad * 8];
#pragma unroll
        for (int nt = 0; nt < 4; nt++)
#pragma unroll
            for (int ks = 0; ks < 2; ks++)
                bfr[nt][ks] = *(const short8*)&lb[(wn + nt * 16 + lane15) * 64
                                                  + ks * 32 + quad * 8];
#pragma unroll
        for (int mt = 0; mt < 4; mt++)
#pragma unroll
            for (int nt = 0; nt < 4; nt++) {
                acc[mt][nt] = __builtin_amdgcn_mfma_f32_16x16x32_bf16(
                    af[mt][0], bfr[nt][0], acc[mt][nt], 0, 0, 0);
                acc[mt][nt] = __builtin_amdgcn_mfma_f32_16x16x32_bf16(
                    af[mt][1], bfr[nt][1], acc[mt][nt], 0, 0, 0);
            }
        cur ^= 1;
    }

    const bool doT = (transZ2 != 0) && (blockIdx.z == 2);
#pragma unroll
    for (int nt = 0; nt < 4; nt++) {
        int gn = n0 + wn + nt * 16 + lane15;
        float bv = Bi[gn];
        if constexpr (sizeof(TY) == 2) {
            if (doT) {   // transposed write: Y[N][M], 4 consecutive m as 8B pack
#pragma unroll
                for (int mt = 0; mt < 4; mt++) {
                    int gm = m0 + wm + mt * 16 + quad * 4;
                    bf16x4 pk;
#pragma unroll
                    for (int r = 0; r < 4; r++) pk[r] = f2bf(acc[mt][nt][r] + bv);
                    *(bf16x4*)&Y[(size_t)gn * M + gm] = pk;
                }
                continue;
            }
        }
#pragma unroll
        for (int mt = 0; mt < 4; mt++) {
            int gm = m0 + wm + mt * 16 + quad * 4;
            size_t base = (size_t)gm * N + gn;
#pragma unroll
            for (int r = 0; r < 4; r++)
                st1(&Y[base + (size_t)r * N], acc[mt][nt][r] + bv);
        }
    }
}

// ---------------------------------------------------------------------------
// Flash attention (no-max softmax, bounded scores). Grid: (S/128, B*H).
// 256 threads (4 waves), each wave owns 32 query rows; 64-key tiles.
// K/V register prefetch. S^T = mfma(K,Q): lane's C regs = 4 consecutive keys
// of one query row -> P stored as [q][k] with ds_write_b64 (XOR-swizzled).
// Row sums via ones-MFMA (l = P*1, C-layout == o rows).
// Qb/Kb/Xo: [B*S][768] bf16, head h = cols h*64..+63. Vt: [768][8192] bf16.
// ---------------------------------------------------------------------------
__global__ __launch_bounds__(256, 2) void attn(
    const unsigned short* __restrict__ Qb, const unsigned short* __restrict__ Kb,
    const unsigned short* __restrict__ Vt, unsigned short* __restrict__ Xo)
{
    const int S = 4096, D = 768, Mtot = 8192;
    // Q tile, reused for P. Stride 64, 8-col-group XOR swizzle: logical
    // element (row, g*8+e) lives at row*64 + ((g ^ (row&7))<<3) + e.
    __shared__ __align__(16) unsigned short lds_qp[128 * 64];
    __shared__ __align__(16) unsigned short lds_k[64 * 72];   // K tile [key][dk]
    __shared__ __align__(16) unsigned short lds_vt[64 * 72];  // V^T tile [dk][key]

    const int tid = threadIdx.x;
    const int wave = tid >> 6, lane = tid & 63;
    const int lane15 = lane & 15, quad = lane >> 4;
    const int x7 = lane15 & 7;               // row&7 for all frag rows below
    const int q0 = blockIdx.x * 128;
    const int b = blockIdx.y / 12, h = blockIdx.y % 12;
    const size_t base_bh = (size_t)b * S * D + (size_t)h * 64;
    const size_t vbase   = (size_t)(h * 64) * Mtot + (size_t)b * S;

    // stage Q tile [128][64] -> lds_qp (swizzled)
#pragma unroll
    for (int i = 0; i < 4; i++) {
        int c = tid + 256 * i;            // 0..1023
        int r = c >> 3;                   // 0..127
        int g = c & 7;                    // 8-col group
        *(ushort8*)&lds_qp[r * 64 + ((g ^ (r & 7)) << 3)] =
            *(const ushort8*)&Qb[base_bh + (size_t)(q0 + r) * D + g * 8];
    }
    __syncthreads();

    short8 qf[2][2];
#pragma unroll
    for (int mt = 0; mt < 2; mt++) {
        int row = wave * 32 + mt * 16 + lane15;
#pragma unroll
        for (int ks = 0; ks < 2; ks++)
            qf[mt][ks] = *(const short8*)&lds_qp[row * 64
                          + (((ks * 4 + quad) ^ x7) << 3)];
    }

    short8 ones;
#pragma unroll
    for (int j = 0; j < 8; j++) ones[j] = (short)0x3F80;   // bf16 1.0

    f32x4 o[2][4] = {};
    f32x4 lacc[2] = {};                    // row sums, C-layout (row=quad*4+r)

    // K/V prefetch registers
    ushort8 kreg[2], vreg[2];
#pragma unroll
    for (int i = 0; i < 2; i++) {
        int c = tid + 256 * i, r = c >> 3, c8 = (c & 7) * 8;
        kreg[i] = *(const ushort8*)&Kb[base_bh + (size_t)r * D + c8];
        vreg[i] = *(const ushort8*)&Vt[vbase + (size_t)r * Mtot + c8];
    }

    for (int kt = 0; kt < 64; kt++) {
        __syncthreads();  // (a) prev-iteration frag reads drained
#pragma unroll
        for (int i = 0; i < 2; i++) {
            int c = tid + 256 * i, r = c >> 3, c8 = (c & 7) * 8;
            *(ushort8*)&lds_k[r * 72 + c8]  = kreg[i];
            *(ushort8*)&lds_vt[r * 72 + c8] = vreg[i];
        }
        __syncthreads();  // (b)

        if (kt < 63) {    // prefetch next tile; overlaps compute below
            const int kn = (kt + 1) * 64;
#pragma unroll
            for (int i = 0; i < 2; i++) {
                int c = tid + 256 * i, r = c >> 3, c8 = (c & 7) * 8;
                kreg[i] = *(const ushort8*)&Kb[base_bh + (size_t)(kn + r) * D + c8];
                vreg[i] = *(const ushort8*)&Vt[vbase + (size_t)r * Mtot + kn + c8];
            }
        }

        // S^T = K Q^T (scale folded into exp2). C: row=key, col=query.
        short8 kf[4][2];
#pragma unroll
        for (int nt = 0; nt < 4; nt++)
#pragma unroll
            for (int ks = 0; ks < 2; ks++)
                kf[nt][ks] = *(const short8*)&lds_k[(nt * 16 + lane15) * 72
                                                    + ks * 32 + quad * 8];
        f32x4 st[2][4];
#pragma unroll
        for (int mt = 0; mt < 2; mt++)
#pragma unroll
            for (int nt = 0; nt < 4; nt++) {
                f32x4 a = {0.f, 0.f, 0.f, 0.f};
                a = __builtin_amdgcn_mfma_f32_16x16x32_bf16(kf[nt][0], qf[mt][0], a, 0, 0, 0);
                a = __builtin_amdgcn_mfma_f32_16x16x32_bf16(kf[nt][1], qf[mt][1], a, 0, 0, 0);
                st[mt][nt] = a;
            }

        // p = exp(s/8) -> truncated bf16, 4 consecutive keys packed -> b64
        // store into own q-row (same-wave DS in-order, no barrier needed)
#pragma unroll
        for (int mt = 0; mt < 2; mt++) {
            int row = wave * 32 + mt * 16 + lane15;
#pragma unroll
            for (int nt = 0; nt < 4; nt++) {
                bf16x4 pk;
#pragma unroll
                for (int r = 0; r < 4; r++) {
                    float p = __builtin_amdgcn_exp2f(st[mt][nt][r] * SCL);
                    unsigned int u = __builtin_bit_cast(unsigned int, p);
                    pk[r] = (unsigned short)(u >> 16);
                }
                int kb = nt * 16 + quad * 4;     // key base (4 consecutive)
                *(bf16x4*)&lds_qp[row * 64 + (((kb >> 3) ^ x7) << 3) + (kb & 7)] = pk;
            }
        }

        short8 pf[2][2], vf[4][2];
#pragma unroll
        for (int mt = 0; mt < 2; mt++) {
            int row = wave * 32 + mt * 16 + lane15;
#pragma unroll
            for (int ks = 0; ks < 2; ks++)
                pf[mt][ks] = *(const short8*)&lds_qp[row * 64
                              + (((ks * 4 + quad) ^ x7) << 3)];
        }
#pragma unroll
        for (int d = 0; d < 4; d++)
#pragma unroll
            for (int ks = 0; ks < 2; ks++)
                vf[d][ks] = *(const short8*)&lds_vt[(d * 16 + lane15) * 72
                                                    + ks * 32 + quad * 8];

        // row sums: l += P * 1  (exactly the stored P -> num/denom consistent)
#pragma unroll
        for (int mt = 0; mt < 2; mt++) {
            lacc[mt] = __builtin_amdgcn_mfma_f32_16x16x32_bf16(pf[mt][0], ones, lacc[mt], 0, 0, 0);
            lacc[mt] = __builtin_amdgcn_mfma_f32_16x16x32_bf16(pf[mt][1], ones, lacc[mt], 0, 0, 0);
        }
#pragma unroll
        for (int mt = 0; mt < 2; mt++)
#pragma unroll
            for (int d = 0; d < 4; d++) {
                o[mt][d] = __builtin_amdgcn_mfma_f32_16x16x32_bf16(pf[mt][0], vf[d][0], o[mt][d], 0, 0, 0);
                o[mt][d] = __builtin_amdgcn_mfma_f32_16x16x32_bf16(pf[mt][1], vf[d][1], o[mt][d], 0, 0, 0);
            }
    }

    // epilogue: lacc C-layout rows == o rows -> direct divide, store
#pragma unroll
    for (int mt = 0; mt < 2; mt++)
#pragma unroll
        for (int r = 0; r < 4; r++) {
            float inv = 1.0f / lacc[mt][r];
            int gq = q0 + wave * 32 + mt * 16 + quad * 4 + r;
            size_t rowoff = base_bh + (size_t)gq * D;
#pragma unroll
            for (int d = 0; d < 4; d++)
                Xo[rowoff + d * 16 + lane15] = f2bf(o[mt][d][r] * inv);
        }
}

extern "C" void kernel_launch(void* const* d_in, const int* in_sizes, int n_in,
                              void* d_out, int out_size, void* d_ws, size_t ws_size,
                              hipStream_t stream) {
    const float* q  = (const float*)d_in[0];
    const float* k  = (const float*)d_in[1];
    const float* v  = (const float*)d_in[2];
    const float* wq = (const float*)d_in[3];
    const float* bq = (const float*)d_in[4];
    const float* wk = (const float*)d_in[5];
    const float* bk = (const float*)d_in[6];
    const float* wv = (const float*)d_in[7];
    const float* bv = (const float*)d_in[8];
    const float* wo = (const float*)d_in[9];
    const float* bo = (const float*)d_in[10];
    float* out = (float*)d_out;

    const int M = 8192, N = 768, K = 768;
    const size_t BIG = (size_t)M * N;        // 6291456
    const size_t WSZ = (size_t)N * K;        // 589824

    unsigned short* ws = (unsigned short*)d_ws;
    unsigned short* qb  = ws;                 // [8192][768]
    unsigned short* kb  = qb + BIG;
    unsigned short* vt  = kb + BIG;           // [768][8192] (V^T)
    unsigned short* xq  = vt + BIG;           // converted inputs
    unsigned short* xk  = xq + BIG;
    unsigned short* xv  = xk + BIG;
    unsigned short* wqb = xv + BIG;           // converted weights
    unsigned short* wkb = wqb + WSZ;
    unsigned short* wvb = wkb + WSZ;
    unsigned short* wob = wvb + WSZ;
    unsigned short* xb  = xq;                 // attn output reuses xq (dead)

    const size_t need = (6 * BIG + 4 * WSZ) * sizeof(unsigned short);

    if (ws_size >= need) {
        // pre-convert inputs + weights to bf16 (grid-stride)
        cvt_bf16<<<dim3(512, 3), 256, 0, stream>>>(
            q, xq, k, xk, v, xv, v, xv, (int)BIG);
        cvt_bf16<<<dim3(96, 4), 256, 0, stream>>>(
            wq, wqb, wk, wkb, wv, wvb, wo, wob, (int)WSZ);

        dim3 g1(M / 128, N / 128, 3);
        gemm_bt<unsigned short, unsigned short, unsigned short>
            <<<g1, 256, 0, stream>>>(xq, wqb, bq, qb,
                                     xk, wkb, bk, kb,
                                     xv, wvb, bv, vt, M, N, K, 1);

        attn<<<dim3(4096 / 128, 2 * 12), 256, 0, stream>>>(qb, kb, vt, xb);

        dim3 g2(M / 128, N / 128, 1);
        gemm_bt<unsigned short, unsigned short, float>
            <<<g2, 256, 0, stream>>>(xb, wob, bo, out,
                                     xb, wob, bo, out,
                                     xb, wob, bo, out, M, N, K, 0);
    } else {
        // fallback: fp32 staging + V^T write + attn
        unsigned short* fqb = ws;
        unsigned short* fkb = fqb + BIG;
        unsigned short* fvt = fkb + BIG;
        unsigned short* fxb = fvt + BIG;

        dim3 g1(M / 128, N / 128, 3);
        gemm_bt<float, float, unsigned short>
            <<<g1, 256, 0, stream>>>(q, wq, bq, fqb,
                                     k, wk, bk, fkb,
                                     v, wv, bv, fvt, M, N, K, 1);

        attn<<<dim3(4096 / 128, 2 * 12), 256, 0, stream>>>(fqb, fkb, fvt, fxb);

        dim3 g2(M / 128, N / 128, 1);
        gemm_bt<unsigned short, float, float>
            <<<g2, 256, 0, stream>>>(fxb, wo, bo, out,
                                     fxb, wo, bo, out,
                                     fxb, wo, bo, out, M, N, K, 0);
    }
}

// Round 3
// 319.237 us; speedup vs baseline: 1.0635x; 1.0635x over previous
//
#include <hip/hip_runtime.h>

// MHA: B=2, S=4096, D=768, H=12, dk=64. Inputs/outputs fp32; compute bf16
// MFMA + fp32 accum. q = X wq^T + bq ; s = q k^T/8 ; p = softmax ; x = p v ;
// out = x wo^T + bo.
//
// R12: (1) GEMM reverted to the R10 single-buffer 3-blocks/CU structure —
// R11's explicit dbuf cost occupancy (3->2) for no overlap gain (matches
// m99/m100: dbuf on the 2-barrier structure is neutral/negative).
// (2) attn: K/V LDS double-buffered -> ONE barrier per k-tile (was two);
// single end-of-iter barrier is sufficient (end-of-t barrier orders all
// reads of buf[t&1] before the end-of-(t+1) write to it). launch_bounds
// (256,3): grid 768 = exactly 3 blocks/CU x 256 CUs, one clean round.
// s_setprio(1) around MFMA clusters (T5; 3 independent blocks/CU -> waves
// at different phases, scheduler has something to arbitrate).

typedef __attribute__((ext_vector_type(8))) short short8;      // MFMA A/B frag
typedef __attribute__((ext_vector_type(8))) unsigned short ushort8;
typedef __attribute__((ext_vector_type(4))) unsigned short bf16x4;  // NOT ushort4 (HIP-reserved)
typedef __attribute__((ext_vector_type(4))) float f32x4;

// exp(s/8) = 2^(s * 0.125 * log2(e))
#define SCL 0.18033688011112042f

__device__ __forceinline__ unsigned short f2bf(float f) {
    unsigned int u = __builtin_bit_cast(unsigned int, f);
    u += 0x7fffu + ((u >> 16) & 1u);          // RNE
    return (unsigned short)(u >> 16);
}

// async global->LDS, 16B per lane; LDS dest must be lane-linear (base + lane*16)
__device__ __forceinline__ void gld16(const void* g, void* l) {
    __builtin_amdgcn_global_load_lds(
        (const __attribute__((address_space(1))) unsigned int*)g,
        (__attribute__((address_space(3))) unsigned int*)l, 16, 0, 0);
}

// load 8 contiguous elements as bf16x8 (converting if fp32)
__device__ __forceinline__ ushort8 ld8(const unsigned short* p) {
    return *(const ushort8*)p;
}
__device__ __forceinline__ ushort8 ld8(const float* p) {
    f32x4 a = *(const f32x4*)p;
    f32x4 b = *(const f32x4*)(p + 4);
    ushort8 r;
    r[0] = f2bf(a[0]); r[1] = f2bf(a[1]); r[2] = f2bf(a[2]); r[3] = f2bf(a[3]);
    r[4] = f2bf(b[0]); r[5] = f2bf(b[1]); r[6] = f2bf(b[2]); r[7] = f2bf(b[3]);
    return r;
}
__device__ __forceinline__ void st1(unsigned short* p, float v) { *p = f2bf(v); }
__device__ __forceinline__ void st1(float* p, float v)          { *p = v; }

// fp32 -> bf16 bulk convert; gridDim.y selects tensor (up to 4); grid-stride
__global__ __launch_bounds__(256) void cvt_bf16(
    const float* __restrict__ s0, unsigned short* __restrict__ d0,
    const float* __restrict__ s1, unsigned short* __restrict__ d1,
    const float* __restrict__ s2, unsigned short* __restrict__ d2,
    const float* __restrict__ s3, unsigned short* __restrict__ d3, int n)
{
    const float* s; unsigned short* d;
    if (blockIdx.y == 0)      { s = s0; d = d0; }
    else if (blockIdx.y == 1) { s = s1; d = d1; }
    else if (blockIdx.y == 2) { s = s2; d = d2; }
    else                      { s = s3; d = d3; }
    const int step = gridDim.x * 2048;            // 256 threads * 8 elems
    for (int i = (blockIdx.x * 256 + threadIdx.x) * 8; i + 8 <= n; i += step) {
        f32x4 a = *(const f32x4*)&s[i];
        f32x4 b = *(const f32x4*)&s[i + 4];
        ushort8 r;
        r[0] = f2bf(a[0]); r[1] = f2bf(a[1]); r[2] = f2bf(a[2]); r[3] = f2bf(a[3]);
        r[4] = f2bf(b[0]); r[5] = f2bf(b[1]); r[6] = f2bf(b[2]); r[7] = f2bf(b[3]);
        *(ushort8*)&d[i] = r;
    }
}

// ---------------------------------------------------------------------------
// GEMM: Y[M,N] = X[M,K] * W[N,K]^T + bias[N], fp32 accum, bf16 MFMA.
// 128x128 tile, BK=64, 4 waves x (64x64). blockIdx.z muxes 3 tuples.
// bf16 inputs -> async global_load_lds staging (lane-linear LDS).
// transZ2: tuple 2 writes Y transposed ([N][M], bf16 only) for V^T.
// (R10 structure: single buffer, 3 blocks/CU — implicit TLP hides latency.)
// ---------------------------------------------------------------------------
template<typename TX, typename TW, typename TY>
__global__ __launch_bounds__(256, 3) void gemm_bt(
    const TX* __restrict__ X0, const TW* __restrict__ W0,
    const float* __restrict__ B0, TY* __restrict__ Y0,
    const TX* __restrict__ X1, const TW* __restrict__ W1,
    const float* __restrict__ B1, TY* __restrict__ Y1,
    const TX* __restrict__ X2, const TW* __restrict__ W2,
    const float* __restrict__ B2, TY* __restrict__ Y2,
    int M, int N, int K, int transZ2)
{
    __shared__ __align__(16) unsigned short lds_a[128 * 64];  // 16 KB
    __shared__ __align__(16) unsigned short lds_b[128 * 64];  // 16 KB

    const TX *X; const TW *W; const float *Bi; TY *Y;
    if (blockIdx.z == 0)      { X = X0; W = W0; Bi = B0; Y = Y0; }
    else if (blockIdx.z == 1) { X = X1; W = W1; Bi = B1; Y = Y1; }
    else                      { X = X2; W = W2; Bi = B2; Y = Y2; }

    const int tid = threadIdx.x;
    const int wave = tid >> 6, lane = tid & 63;
    const int lane15 = lane & 15, quad = lane >> 4;
    const int m0 = blockIdx.x * 128, n0 = blockIdx.y * 128;
    const int wm = (wave & 1) * 64, wn = (wave >> 1) * 64;

    f32x4 acc[4][4] = {};

    for (int k0 = 0; k0 < K; k0 += 64) {
        __syncthreads();
#pragma unroll
        for (int i = 0; i < 4; i++) {
            int c  = tid + 256 * i;            // 0..1023 chunks of 8 elems
            int r  = c >> 3;                   // 0..127
            int c8 = (c & 7) * 8;              // 0..56
            if constexpr (sizeof(TX) == 2 && sizeof(TW) == 2) {
                gld16(&X[(size_t)(m0 + r) * K + k0 + c8], &lds_a[c * 8]);
                gld16(&W[(size_t)(n0 + r) * K + k0 + c8], &lds_b[c * 8]);
            } else {
                *(ushort8*)&lds_a[r * 64 + c8] = ld8(&X[(size_t)(m0 + r) * K + k0 + c8]);
                *(ushort8*)&lds_b[r * 64 + c8] = ld8(&W[(size_t)(n0 + r) * K + k0 + c8]);
            }
        }
        __syncthreads();

        short8 af[4][2], bfr[4][2];
#pragma unroll
        for (int mt = 0; mt < 4; mt++)
#pragma unroll
            for (int ks = 0; ks < 2; ks++)
                af[mt][ks] = *(const short8*)&lds_a[(wm + mt * 16 + lane15) * 64
                                                    + ks * 32 + quad * 8];
#pragma unroll
        for (int nt = 0; nt < 4; nt++)
#pragma unroll
            for (int ks = 0; ks < 2; ks++)
                bfr[nt][ks] = *(const short8*)&lds_b[(wn + nt * 16 + lane15) * 64
                                                     + ks * 32 + quad * 8];
#pragma unroll
        for (int mt = 0; mt < 4; mt++)
#pragma unroll
            for (int nt = 0; nt < 4; nt++) {
                acc[mt][nt] = __builtin_amdgcn_mfma_f32_16x16x32_bf16(
                    af[mt][0], bfr[nt][0], acc[mt][nt], 0, 0, 0);
                acc[mt][nt] = __builtin_amdgcn_mfma_f32_16x16x32_bf16(
                    af[mt][1], bfr[nt][1], acc[mt][nt], 0, 0, 0);
            }
    }

    const bool doT = (transZ2 != 0) && (blockIdx.z == 2);
#pragma unroll
    for (int nt = 0; nt < 4; nt++) {
        int gn = n0 + wn + nt * 16 + lane15;
        float bv = Bi[gn];
        if constexpr (sizeof(TY) == 2) {
            if (doT) {   // transposed write: Y[N][M], 4 consecutive m as 8B pack
#pragma unroll
                for (int mt = 0; mt < 4; mt++) {
                    int gm = m0 + wm + mt * 16 + quad * 4;
                    bf16x4 pk;
#pragma unroll
                    for (int r = 0; r < 4; r++) pk[r] = f2bf(acc[mt][nt][r] + bv);
                    *(bf16x4*)&Y[(size_t)gn * M + gm] = pk;
                }
                continue;
            }
        }
#pragma unroll
        for (int mt = 0; mt < 4; mt++) {
            int gm = m0 + wm + mt * 16 + quad * 4;
            size_t base = (size_t)gm * N + gn;
#pragma unroll
            for (int r = 0; r < 4; r++)
                st1(&Y[base + (size_t)r * N], acc[mt][nt][r] + bv);
        }
    }
}

// ---------------------------------------------------------------------------
// Flash attention (no-max softmax, bounded scores). Grid: (S/128, B*H).
// 256 threads (4 waves), each wave owns 32 query rows; 64-key tiles.
// K/V LDS double-buffered -> 1 barrier per tile. K/V register prefetch.
// S^T = mfma(K,Q): lane's C regs = 4 consecutive keys of one query row ->
// P stored as [q][k] with ds_write_b64 (XOR-swizzled). Row sums via
// ones-MFMA (l = P*1, C-layout == o rows). setprio around MFMA clusters.
// Qb/Kb/Xo: [B*S][768] bf16, head h = cols h*64..+63. Vt: [768][8192] bf16.
// ---------------------------------------------------------------------------
__global__ __launch_bounds__(256, 3) void attn(
    const unsigned short* __restrict__ Qb, const unsigned short* __restrict__ Kb,
    const unsigned short* __restrict__ Vt, unsigned short* __restrict__ Xo)
{
    const int S = 4096, D = 768, Mtot = 8192;
    // Q tile, reused for P. Stride 64, 8-col-group XOR swizzle: logical
    // element (row, g*8+e) lives at row*64 + ((g ^ (row&7))<<3) + e.
    __shared__ __align__(16) unsigned short lds_qp[128 * 64];     // 16 KB
    __shared__ __align__(16) unsigned short lds_k[2][64 * 72];    // 18 KB
    __shared__ __align__(16) unsigned short lds_vt[2][64 * 72];   // 18 KB

    const int tid = threadIdx.x;
    const int wave = tid >> 6, lane = tid & 63;
    const int lane15 = lane & 15, quad = lane >> 4;
    const int x7 = lane15 & 7;               // row&7 for all frag rows below
    const int q0 = blockIdx.x * 128;
    const int b = blockIdx.y / 12, h = blockIdx.y % 12;
    const size_t base_bh = (size_t)b * S * D + (size_t)h * 64;
    const size_t vbase   = (size_t)(h * 64) * Mtot + (size_t)b * S;

    // per-thread staging coords (8 ushort8 chunks per 64x64 tile, 2/thread)
    const int c0 = tid, r0 = c0 >> 3, c80 = (c0 & 7) * 8;
    const int c1 = tid + 256, r1 = c1 >> 3, c81 = (c1 & 7) * 8;

    // K/V prefetch registers: tile 0
    ushort8 kreg[2], vreg[2];
    kreg[0] = *(const ushort8*)&Kb[base_bh + (size_t)r0 * D + c80];
    kreg[1] = *(const ushort8*)&Kb[base_bh + (size_t)r1 * D + c81];
    vreg[0] = *(const ushort8*)&Vt[vbase + (size_t)r0 * Mtot + c80];
    vreg[1] = *(const ushort8*)&Vt[vbase + (size_t)r1 * Mtot + c81];

    // stage Q tile [128][64] -> lds_qp (swizzled)
#pragma unroll
    for (int i = 0; i < 4; i++) {
        int c = tid + 256 * i;            // 0..1023
        int r = c >> 3;                   // 0..127
        int g = c & 7;                    // 8-col group
        *(ushort8*)&lds_qp[r * 64 + ((g ^ (r & 7)) << 3)] =
            *(const ushort8*)&Qb[base_bh + (size_t)(q0 + r) * D + g * 8];
    }
    // write K/V tile 0 into buffer 0
    *(ushort8*)&lds_k[0][r0 * 72 + c80]  = kreg[0];
    *(ushort8*)&lds_k[0][r1 * 72 + c81]  = kreg[1];
    *(ushort8*)&lds_vt[0][r0 * 72 + c80] = vreg[0];
    *(ushort8*)&lds_vt[0][r1 * 72 + c81] = vreg[1];
    __syncthreads();

    short8 qf[2][2];
#pragma unroll
    for (int mt = 0; mt < 2; mt++) {
        int row = wave * 32 + mt * 16 + lane15;
#pragma unroll
        for (int ks = 0; ks < 2; ks++)
            qf[mt][ks] = *(const short8*)&lds_qp[row * 64
                          + (((ks * 4 + quad) ^ x7) << 3)];
    }

    short8 ones;
#pragma unroll
    for (int j = 0; j < 8; j++) ones[j] = (short)0x3F80;   // bf16 1.0

    f32x4 o[2][4] = {};
    f32x4 lacc[2] = {};                    // row sums, C-layout (row=quad*4+r)

    for (int kt = 0; kt < 64; kt++) {
        const int cur = kt & 1;
        if (kt < 63) {    // prefetch next tile; overlaps compute below
            const int kn = (kt + 1) * 64;
            kreg[0] = *(const ushort8*)&Kb[base_bh + (size_t)(kn + r0) * D + c80];
            kreg[1] = *(const ushort8*)&Kb[base_bh + (size_t)(kn + r1) * D + c81];
            vreg[0] = *(const ushort8*)&Vt[vbase + (size_t)r0 * Mtot + kn + c80];
            vreg[1] = *(const ushort8*)&Vt[vbase + (size_t)r1 * Mtot + kn + c81];
        }

        // S^T = K Q^T (scale folded into exp2). C: row=key, col=query.
        short8 kf[4][2];
#pragma unroll
        for (int nt = 0; nt < 4; nt++)
#pragma unroll
            for (int ks = 0; ks < 2; ks++)
                kf[nt][ks] = *(const short8*)&lds_k[cur][(nt * 16 + lane15) * 72
                                                         + ks * 32 + quad * 8];
        f32x4 st[2][4];
        __builtin_amdgcn_s_setprio(1);
#pragma unroll
        for (int mt = 0; mt < 2; mt++)
#pragma unroll
            for (int nt = 0; nt < 4; nt++) {
                f32x4 a = {0.f, 0.f, 0.f, 0.f};
                a = __builtin_amdgcn_mfma_f32_16x16x32_bf16(kf[nt][0], qf[mt][0], a, 0, 0, 0);
                a = __builtin_amdgcn_mfma_f32_16x16x32_bf16(kf[nt][1], qf[mt][1], a, 0, 0, 0);
                st[mt][nt] = a;
            }
        __builtin_amdgcn_s_setprio(0);

        // p = exp(s/8) -> truncated bf16, 4 consecutive keys packed -> b64
        // store into own q-row (same-wave DS in-order, no barrier needed)
#pragma unroll
        for (int mt = 0; mt < 2; mt++) {
            int row = wave * 32 + mt * 16 + lane15;
#pragma unroll
            for (int nt = 0; nt < 4; nt++) {
                bf16x4 pk;
#pragma unroll
                for (int r = 0; r < 4; r++) {
                    float p = __builtin_amdgcn_exp2f(st[mt][nt][r] * SCL);
                    unsigned int u = __builtin_bit_cast(unsigned int, p);
                    pk[r] = (unsigned short)(u >> 16);
                }
                int kb = nt * 16 + quad * 4;     // key base (4 consecutive)
                *(bf16x4*)&lds_qp[row * 64 + (((kb >> 3) ^ x7) << 3) + (kb & 7)] = pk;
            }
        }

        short8 pf[2][2], vf[4][2];
#pragma unroll
        for (int mt = 0; mt < 2; mt++) {
            int row = wave * 32 + mt * 16 + lane15;
#pragma unroll
            for (int ks = 0; ks < 2; ks++)
                pf[mt][ks] = *(const short8*)&lds_qp[row * 64
                              + (((ks * 4 + quad) ^ x7) << 3)];
        }
#pragma unroll
        for (int d = 0; d < 4; d++)
#pragma unroll
            for (int ks = 0; ks < 2; ks++)
                vf[d][ks] = *(const short8*)&lds_vt[cur][(d * 16 + lane15) * 72
                                                         + ks * 32 + quad * 8];

        // row sums: l += P * 1  (exactly the stored P -> num/denom consistent)
        __builtin_amdgcn_s_setprio(1);
#pragma unroll
        for (int mt = 0; mt < 2; mt++) {
            lacc[mt] = __builtin_amdgcn_mfma_f32_16x16x32_bf16(pf[mt][0], ones, lacc[mt], 0, 0, 0);
            lacc[mt] = __builtin_amdgcn_mfma_f32_16x16x32_bf16(pf[mt][1], ones, lacc[mt], 0, 0, 0);
        }
#pragma unroll
        for (int mt = 0; mt < 2; mt++)
#pragma unroll
            for (int d = 0; d < 4; d++) {
                o[mt][d] = __builtin_amdgcn_mfma_f32_16x16x32_bf16(pf[mt][0], vf[d][0], o[mt][d], 0, 0, 0);
                o[mt][d] = __builtin_amdgcn_mfma_f32_16x16x32_bf16(pf[mt][1], vf[d][1], o[mt][d], 0, 0, 0);
            }
        __builtin_amdgcn_s_setprio(0);

        if (kt < 63) {
            // write next K/V tile into the other buffer; that buffer's last
            // readers (iter kt-1) are ordered before us by the end-of-(kt-1)
            // barrier, and this barrier publishes our writes for iter kt+1.
            *(ushort8*)&lds_k[cur ^ 1][r0 * 72 + c80]  = kreg[0];
            *(ushort8*)&lds_k[cur ^ 1][r1 * 72 + c81]  = kreg[1];
            *(ushort8*)&lds_vt[cur ^ 1][r0 * 72 + c80] = vreg[0];
            *(ushort8*)&lds_vt[cur ^ 1][r1 * 72 + c81] = vreg[1];
            __syncthreads();
        }
    }

    // epilogue: lacc C-layout rows == o rows -> direct divide, store
#pragma unroll
    for (int mt = 0; mt < 2; mt++)
#pragma unroll
        for (int r = 0; r < 4; r++) {
            float inv = 1.0f / lacc[mt][r];
            int gq = q0 + wave * 32 + mt * 16 + quad * 4 + r;
            size_t rowoff = base_bh + (size_t)gq * D;
#pragma unroll
            for (int d = 0; d < 4; d++)
                Xo[rowoff + d * 16 + lane15] = f2bf(o[mt][d][r] * inv);
        }
}

extern "C" void kernel_launch(void* const* d_in, const int* in_sizes, int n_in,
                              void* d_out, int out_size, void* d_ws, size_t ws_size,
                              hipStream_t stream) {
    const float* q  = (const float*)d_in[0];
    const float* k  = (const float*)d_in[1];
    const float* v  = (const float*)d_in[2];
    const float* wq = (const float*)d_in[3];
    const float* bq = (const float*)d_in[4];
    const float* wk = (const float*)d_in[5];
    const float* bk = (const float*)d_in[6];
    const float* wv = (const float*)d_in[7];
    const float* bv = (const float*)d_in[8];
    const float* wo = (const float*)d_in[9];
    const float* bo = (const float*)d_in[10];
    float* out = (float*)d_out;

    const int M = 8192, N = 768, K = 768;
    const size_t BIG = (size_t)M * N;        // 6291456
    const size_t WSZ = (size_t)N * K;        // 589824

    unsigned short* ws = (unsigned short*)d_ws;
    unsigned short* qb  = ws;                 // [8192][768]
    unsigned short* kb  = qb + BIG;
    unsigned short* vt  = kb + BIG;           // [768][8192] (V^T)
    unsigned short* xq  = vt + BIG;           // converted inputs
    unsigned short* xk  = xq + BIG;
    unsigned short* xv  = xk + BIG;
    unsigned short* wqb = xv + BIG;           // converted weights
    unsigned short* wkb = wqb + WSZ;
    unsigned short* wvb = wkb + WSZ;
    unsigned short* wob = wvb + WSZ;
    unsigned short* xb  = xq;                 // attn output reuses xq (dead)

    const size_t need = (6 * BIG + 4 * WSZ) * sizeof(unsigned short);

    if (ws_size >= need) {
        // pre-convert inputs + weights to bf16 (grid-stride)
        cvt_bf16<<<dim3(512, 3), 256, 0, stream>>>(
            q, xq, k, xk, v, xv, v, xv, (int)BIG);
        cvt_bf16<<<dim3(96, 4), 256, 0, stream>>>(
            wq, wqb, wk, wkb, wv, wvb, wo, wob, (int)WSZ);

        dim3 g1(M / 128, N / 128, 3);
        gemm_bt<unsigned short, unsigned short, unsigned short>
            <<<g1, 256, 0, stream>>>(xq, wqb, bq, qb,
                                     xk, wkb, bk, kb,
                                     xv, wvb, bv, vt, M, N, K, 1);

        attn<<<dim3(4096 / 128, 2 * 12), 256, 0, stream>>>(qb, kb, vt, xb);

        dim3 g2(M / 128, N / 128, 1);
        gemm_bt<unsigned short, unsigned short, float>
            <<<g2, 256, 0, stream>>>(xb, wob, bo, out,
                                     xb, wob, bo, out,
                                     xb, wob, bo, out, M, N, K, 0);
    } else {
        // fallback: fp32 staging + V^T write + attn
        unsigned short* fqb = ws;
        unsigned short* fkb = fqb + BIG;
        unsigned short* fvt = fkb + BIG;
        unsigned short* fxb = fvt + BIG;

        dim3 g1(M / 128, N / 128, 3);
        gemm_bt<float, float, unsigned short>
            <<<g1, 256, 0, stream>>>(q, wq, bq, fqb,
                                     k, wk, bk, fkb,
                                     v, wv, bv, fvt, M, N, K, 1);

        attn<<<dim3(4096 / 128, 2 * 12), 256, 0, stream>>>(fqb, fkb, fvt, fxb);

        dim3 g2(M / 128, N / 128, 1);
        gemm_bt<unsigned short, float, float>
            <<<g2, 256, 0, stream>>>(fxb, wo, bo, out,
                                     fxb, wo, bo, out,
                                     fxb, wo, bo, out, M, N, K, 0);
    }
}

// Round 4
// 307.957 us; speedup vs baseline: 1.1024x; 1.0366x over previous
//
#include <hip/hip_runtime.h>

// MHA: B=2, S=4096, D=768, H=12, dk=64. Inputs/outputs fp32; compute bf16
// MFMA + fp32 accum. q = X wq^T + bq ; s = q k^T/8 ; p = softmax ; x = p v ;
// out = x wo^T + bo.
//
// R13: (1) gemm_bt templated on NFR (n-frags per wave). gemm1 uses 128x96
// tiles -> grid 64x8x3 = 1536 blocks = exactly 2 full occupancy epochs at
// 3 blocks/CU (was 1152 = 1.5 epochs, ~33% tail waste). gemm2 uses 128x64
// tiles -> grid 64x12 = 768 = exactly 1 full epoch (was 384 blocks = 1.5
// resident/CU, TLP-starved). (2) softmax scale folded into gemm1's tuple-0
// epilogue (yscale=SCL): attn's exp2 input needs no per-element multiply
// (one fp32 mul + one bf16 rounding either way -> numerics unchanged).
// attn otherwise = R12 (K/V dbuf, 1 barrier/tile, setprio, swizzled P).

typedef __attribute__((ext_vector_type(8))) short short8;      // MFMA A/B frag
typedef __attribute__((ext_vector_type(8))) unsigned short ushort8;
typedef __attribute__((ext_vector_type(4))) unsigned short bf16x4;  // NOT ushort4 (HIP-reserved)
typedef __attribute__((ext_vector_type(4))) float f32x4;

// exp(s/8) = 2^(s * 0.125 * log2(e)); folded into Q-projection output
#define SCL 0.18033688011112042f

__device__ __forceinline__ unsigned short f2bf(float f) {
    unsigned int u = __builtin_bit_cast(unsigned int, f);
    u += 0x7fffu + ((u >> 16) & 1u);          // RNE
    return (unsigned short)(u >> 16);
}

// async global->LDS, 16B per lane; LDS dest must be lane-linear (base + lane*16)
__device__ __forceinline__ void gld16(const void* g, void* l) {
    __builtin_amdgcn_global_load_lds(
        (const __attribute__((address_space(1))) unsigned int*)g,
        (__attribute__((address_space(3))) unsigned int*)l, 16, 0, 0);
}

// load 8 contiguous elements as bf16x8 (converting if fp32)
__device__ __forceinline__ ushort8 ld8(const unsigned short* p) {
    return *(const ushort8*)p;
}
__device__ __forceinline__ ushort8 ld8(const float* p) {
    f32x4 a = *(const f32x4*)p;
    f32x4 b = *(const f32x4*)(p + 4);
    ushort8 r;
    r[0] = f2bf(a[0]); r[1] = f2bf(a[1]); r[2] = f2bf(a[2]); r[3] = f2bf(a[3]);
    r[4] = f2bf(b[0]); r[5] = f2bf(b[1]); r[6] = f2bf(b[2]); r[7] = f2bf(b[3]);
    return r;
}
__device__ __forceinline__ void st1(unsigned short* p, float v) { *p = f2bf(v); }
__device__ __forceinline__ void st1(float* p, float v)          { *p = v; }

// fp32 -> bf16 bulk convert; gridDim.y selects tensor (up to 4); grid-stride
__global__ __launch_bounds__(256) void cvt_bf16(
    const float* __restrict__ s0, unsigned short* __restrict__ d0,
    const float* __restrict__ s1, unsigned short* __restrict__ d1,
    const float* __restrict__ s2, unsigned short* __restrict__ d2,
    const float* __restrict__ s3, unsigned short* __restrict__ d3, int n)
{
    const float* s; unsigned short* d;
    if (blockIdx.y == 0)      { s = s0; d = d0; }
    else if (blockIdx.y == 1) { s = s1; d = d1; }
    else if (blockIdx.y == 2) { s = s2; d = d2; }
    else                      { s = s3; d = d3; }
    const int step = gridDim.x * 2048;            // 256 threads * 8 elems
    for (int i = (blockIdx.x * 256 + threadIdx.x) * 8; i + 8 <= n; i += step) {
        f32x4 a = *(const f32x4*)&s[i];
        f32x4 b = *(const f32x4*)&s[i + 4];
        ushort8 r;
        r[0] = f2bf(a[0]); r[1] = f2bf(a[1]); r[2] = f2bf(a[2]); r[3] = f2bf(a[3]);
        r[4] = f2bf(b[0]); r[5] = f2bf(b[1]); r[6] = f2bf(b[2]); r[7] = f2bf(b[3]);
        *(ushort8*)&d[i] = r;
    }
}

// ---------------------------------------------------------------------------
// GEMM: Y[M,N] = X[M,K] * W[N,K]^T + bias[N], fp32 accum, bf16 MFMA.
// Tile 128 x (NFR*32), BK=64, 4 waves x (64 x NFR*16). blockIdx.z muxes 3
// tuples. bf16 inputs -> async global_load_lds staging (lane-linear LDS).
// transZ2: tuple 2 writes Y transposed ([N][M], bf16 only) for V^T.
// ysc0: scale applied to tuple-0 output (folds softmax scale into Q).
// ---------------------------------------------------------------------------
template<int NFR, typename TX, typename TW, typename TY>
__global__ __launch_bounds__(256, 3) void gemm_bt(
    const TX* __restrict__ X0, const TW* __restrict__ W0,
    const float* __restrict__ B0, TY* __restrict__ Y0,
    const TX* __restrict__ X1, const TW* __restrict__ W1,
    const float* __restrict__ B1, TY* __restrict__ Y1,
    const TX* __restrict__ X2, const TW* __restrict__ W2,
    const float* __restrict__ B2, TY* __restrict__ Y2,
    int M, int N, int K, int transZ2, float ysc0)
{
    __shared__ __align__(16) unsigned short lds_a[128 * 64];       // 16 KB
    __shared__ __align__(16) unsigned short lds_b[NFR * 32 * 64];  // 12/8 KB

    const TX *X; const TW *W; const float *Bi; TY *Y;
    if (blockIdx.z == 0)      { X = X0; W = W0; Bi = B0; Y = Y0; }
    else if (blockIdx.z == 1) { X = X1; W = W1; Bi = B1; Y = Y1; }
    else                      { X = X2; W = W2; Bi = B2; Y = Y2; }
    const float ysc = (blockIdx.z == 0) ? ysc0 : 1.0f;

    const int tid = threadIdx.x;
    const int wave = tid >> 6, lane = tid & 63;
    const int lane15 = lane & 15, quad = lane >> 4;
    const int m0 = blockIdx.x * 128, n0 = blockIdx.y * (NFR * 32);
    const int wm = (wave & 1) * 64, wn = (wave >> 1) * (NFR * 16);

    f32x4 acc[4][NFR] = {};

    for (int k0 = 0; k0 < K; k0 += 64) {
        __syncthreads();
#pragma unroll
        for (int i = 0; i < 4; i++) {          // A: 128 rows = 1024 chunks
            int c  = tid + 256 * i;
            int r  = c >> 3;
            int c8 = (c & 7) * 8;
            if constexpr (sizeof(TX) == 2) {
                gld16(&X[(size_t)(m0 + r) * K + k0 + c8], &lds_a[c * 8]);
            } else {
                *(ushort8*)&lds_a[r * 64 + c8] = ld8(&X[(size_t)(m0 + r) * K + k0 + c8]);
            }
        }
#pragma unroll
        for (int i = 0; i < NFR; i++) {        // B: NFR*32 rows = NFR*256 chunks
            int c  = tid + 256 * i;
            int r  = c >> 3;
            int c8 = (c & 7) * 8;
            if constexpr (sizeof(TW) == 2) {
                gld16(&W[(size_t)(n0 + r) * K + k0 + c8], &lds_b[c * 8]);
            } else {
                *(ushort8*)&lds_b[r * 64 + c8] = ld8(&W[(size_t)(n0 + r) * K + k0 + c8]);
            }
        }
        __syncthreads();

        short8 af[4][2], bfr[NFR][2];
#pragma unroll
        for (int mt = 0; mt < 4; mt++)
#pragma unroll
            for (int ks = 0; ks < 2; ks++)
                af[mt][ks] = *(const short8*)&lds_a[(wm + mt * 16 + lane15) * 64
                                                    + ks * 32 + quad * 8];
#pragma unroll
        for (int nt = 0; nt < NFR; nt++)
#pragma unroll
            for (int ks = 0; ks < 2; ks++)
                bfr[nt][ks] = *(const short8*)&lds_b[(wn + nt * 16 + lane15) * 64
                                                     + ks * 32 + quad * 8];
#pragma unroll
        for (int mt = 0; mt < 4; mt++)
#pragma unroll
            for (int nt = 0; nt < NFR; nt++) {
                acc[mt][nt] = __builtin_amdgcn_mfma_f32_16x16x32_bf16(
                    af[mt][0], bfr[nt][0], acc[mt][nt], 0, 0, 0);
                acc[mt][nt] = __builtin_amdgcn_mfma_f32_16x16x32_bf16(
                    af[mt][1], bfr[nt][1], acc[mt][nt], 0, 0, 0);
            }
    }

    const bool doT = (transZ2 != 0) && (blockIdx.z == 2);
#pragma unroll
    for (int nt = 0; nt < NFR; nt++) {
        int gn = n0 + wn + nt * 16 + lane15;
        float bv = Bi[gn];
        if constexpr (sizeof(TY) == 2) {
            if (doT) {   // transposed write: Y[N][M], 4 consecutive m as 8B pack
#pragma unroll
                for (int mt = 0; mt < 4; mt++) {
                    int gm = m0 + wm + mt * 16 + quad * 4;
                    bf16x4 pk;
#pragma unroll
                    for (int r = 0; r < 4; r++) pk[r] = f2bf(acc[mt][nt][r] + bv);
                    *(bf16x4*)&Y[(size_t)gn * M + gm] = pk;
                }
                continue;
            }
        }
#pragma unroll
        for (int mt = 0; mt < 4; mt++) {
            int gm = m0 + wm + mt * 16 + quad * 4;
            size_t base = (size_t)gm * N + gn;
#pragma unroll
            for (int r = 0; r < 4; r++)
                st1(&Y[base + (size_t)r * N], (acc[mt][nt][r] + bv) * ysc);
        }
    }
}

// ---------------------------------------------------------------------------
// Flash attention (no-max softmax, bounded scores). Grid: (S/128, B*H).
// 256 threads (4 waves), each wave owns 32 query rows; 64-key tiles.
// K/V LDS double-buffered -> 1 barrier per tile. K/V register prefetch.
// S^T = mfma(K,Q): lane's C regs = 4 consecutive keys of one query row ->
// P stored as [q][k] with ds_write_b64 (XOR-swizzled). Row sums via
// ones-MFMA (l = P*1, C-layout == o rows). setprio around MFMA clusters.
// Q arrives pre-scaled by SCL (folded into gemm1) -> exp2 input is direct.
// Qb/Kb/Xo: [B*S][768] bf16, head h = cols h*64..+63. Vt: [768][8192] bf16.
// ---------------------------------------------------------------------------
__global__ __launch_bounds__(256, 3) void attn(
    const unsigned short* __restrict__ Qb, const unsigned short* __restrict__ Kb,
    const unsigned short* __restrict__ Vt, unsigned short* __restrict__ Xo)
{
    const int S = 4096, D = 768, Mtot = 8192;
    // Q tile, reused for P. Stride 64, 8-col-group XOR swizzle: logical
    // element (row, g*8+e) lives at row*64 + ((g ^ (row&7))<<3) + e.
    __shared__ __align__(16) unsigned short lds_qp[128 * 64];     // 16 KB
    __shared__ __align__(16) unsigned short lds_k[2][64 * 72];    // 18 KB
    __shared__ __align__(16) unsigned short lds_vt[2][64 * 72];   // 18 KB

    const int tid = threadIdx.x;
    const int wave = tid >> 6, lane = tid & 63;
    const int lane15 = lane & 15, quad = lane >> 4;
    const int x7 = lane15 & 7;               // row&7 for all frag rows below
    const int q0 = blockIdx.x * 128;
    const int b = blockIdx.y / 12, h = blockIdx.y % 12;
    const size_t base_bh = (size_t)b * S * D + (size_t)h * 64;
    const size_t vbase   = (size_t)(h * 64) * Mtot + (size_t)b * S;

    // per-thread staging coords (8 ushort8 chunks per 64x64 tile, 2/thread)
    const int c0 = tid, r0 = c0 >> 3, c80 = (c0 & 7) * 8;
    const int c1 = tid + 256, r1 = c1 >> 3, c81 = (c1 & 7) * 8;

    // K/V prefetch registers: tile 0
    ushort8 kreg[2], vreg[2];
    kreg[0] = *(const ushort8*)&Kb[base_bh + (size_t)r0 * D + c80];
    kreg[1] = *(const ushort8*)&Kb[base_bh + (size_t)r1 * D + c81];
    vreg[0] = *(const ushort8*)&Vt[vbase + (size_t)r0 * Mtot + c80];
    vreg[1] = *(const ushort8*)&Vt[vbase + (size_t)r1 * Mtot + c81];

    // stage Q tile [128][64] -> lds_qp (swizzled)
#pragma unroll
    for (int i = 0; i < 4; i++) {
        int c = tid + 256 * i;            // 0..1023
        int r = c >> 3;                   // 0..127
        int g = c & 7;                    // 8-col group
        *(ushort8*)&lds_qp[r * 64 + ((g ^ (r & 7)) << 3)] =
            *(const ushort8*)&Qb[base_bh + (size_t)(q0 + r) * D + g * 8];
    }
    // write K/V tile 0 into buffer 0
    *(ushort8*)&lds_k[0][r0 * 72 + c80]  = kreg[0];
    *(ushort8*)&lds_k[0][r1 * 72 + c81]  = kreg[1];
    *(ushort8*)&lds_vt[0][r0 * 72 + c80] = vreg[0];
    *(ushort8*)&lds_vt[0][r1 * 72 + c81] = vreg[1];
    __syncthreads();

    short8 qf[2][2];
#pragma unroll
    for (int mt = 0; mt < 2; mt++) {
        int row = wave * 32 + mt * 16 + lane15;
#pragma unroll
        for (int ks = 0; ks < 2; ks++)
            qf[mt][ks] = *(const short8*)&lds_qp[row * 64
                          + (((ks * 4 + quad) ^ x7) << 3)];
    }

    short8 ones;
#pragma unroll
    for (int j = 0; j < 8; j++) ones[j] = (short)0x3F80;   // bf16 1.0

    f32x4 o[2][4] = {};
    f32x4 lacc[2] = {};                    // row sums, C-layout (row=quad*4+r)

    for (int kt = 0; kt < 64; kt++) {
        const int cur = kt & 1;
        if (kt < 63) {    // prefetch next tile; overlaps compute below
            const int kn = (kt + 1) * 64;
            kreg[0] = *(const ushort8*)&Kb[base_bh + (size_t)(kn + r0) * D + c80];
            kreg[1] = *(const ushort8*)&Kb[base_bh + (size_t)(kn + r1) * D + c81];
            vreg[0] = *(const ushort8*)&Vt[vbase + (size_t)r0 * Mtot + kn + c80];
            vreg[1] = *(const ushort8*)&Vt[vbase + (size_t)r1 * Mtot + kn + c81];
        }

        // S^T = K Q^T (pre-scaled Q). C: row=key, col=query.
        short8 kf[4][2];
#pragma unroll
        for (int nt = 0; nt < 4; nt++)
#pragma unroll
            for (int ks = 0; ks < 2; ks++)
                kf[nt][ks] = *(const short8*)&lds_k[cur][(nt * 16 + lane15) * 72
                                                         + ks * 32 + quad * 8];
        f32x4 st[2][4];
        __builtin_amdgcn_s_setprio(1);
#pragma unroll
        for (int mt = 0; mt < 2; mt++)
#pragma unroll
            for (int nt = 0; nt < 4; nt++) {
                f32x4 a = {0.f, 0.f, 0.f, 0.f};
                a = __builtin_amdgcn_mfma_f32_16x16x32_bf16(kf[nt][0], qf[mt][0], a, 0, 0, 0);
                a = __builtin_amdgcn_mfma_f32_16x16x32_bf16(kf[nt][1], qf[mt][1], a, 0, 0, 0);
                st[mt][nt] = a;
            }
        __builtin_amdgcn_s_setprio(0);

        // p = exp2(s') -> truncated bf16, 4 consecutive keys packed -> b64
        // store into own q-row (same-wave DS in-order, no barrier needed)
#pragma unroll
        for (int mt = 0; mt < 2; mt++) {
            int row = wave * 32 + mt * 16 + lane15;
#pragma unroll
            for (int nt = 0; nt < 4; nt++) {
                bf16x4 pk;
#pragma unroll
                for (int r = 0; r < 4; r++) {
                    float p = __builtin_amdgcn_exp2f(st[mt][nt][r]);
                    unsigned int u = __builtin_bit_cast(unsigned int, p);
                    pk[r] = (unsigned short)(u >> 16);
                }
                int kb = nt * 16 + quad * 4;     // key base (4 consecutive)
                *(bf16x4*)&lds_qp[row * 64 + (((kb >> 3) ^ x7) << 3) + (kb & 7)] = pk;
            }
        }

        short8 pf[2][2], vf[4][2];
#pragma unroll
        for (int mt = 0; mt < 2; mt++) {
            int row = wave * 32 + mt * 16 + lane15;
#pragma unroll
            for (int ks = 0; ks < 2; ks++)
                pf[mt][ks] = *(const short8*)&lds_qp[row * 64
                              + (((ks * 4 + quad) ^ x7) << 3)];
        }
#pragma unroll
        for (int d = 0; d < 4; d++)
#pragma unroll
            for (int ks = 0; ks < 2; ks++)
                vf[d][ks] = *(const short8*)&lds_vt[cur][(d * 16 + lane15) * 72
                                                         + ks * 32 + quad * 8];

        // row sums: l += P * 1  (exactly the stored P -> num/denom consistent)
        __builtin_amdgcn_s_setprio(1);
#pragma unroll
        for (int mt = 0; mt < 2; mt++) {
            lacc[mt] = __builtin_amdgcn_mfma_f32_16x16x32_bf16(pf[mt][0], ones, lacc[mt], 0, 0, 0);
            lacc[mt] = __builtin_amdgcn_mfma_f32_16x16x32_bf16(pf[mt][1], ones, lacc[mt], 0, 0, 0);
        }
#pragma unroll
        for (int mt = 0; mt < 2; mt++)
#pragma unroll
            for (int d = 0; d < 4; d++) {
                o[mt][d] = __builtin_amdgcn_mfma_f32_16x16x32_bf16(pf[mt][0], vf[d][0], o[mt][d], 0, 0, 0);
                o[mt][d] = __builtin_amdgcn_mfma_f32_16x16x32_bf16(pf[mt][1], vf[d][1], o[mt][d], 0, 0, 0);
            }
        __builtin_amdgcn_s_setprio(0);

        if (kt < 63) {
            // write next K/V tile into the other buffer; that buffer's last
            // readers (iter kt-1) are ordered before us by the end-of-(kt-1)
            // barrier, and this barrier publishes our writes for iter kt+1.
            *(ushort8*)&lds_k[cur ^ 1][r0 * 72 + c80]  = kreg[0];
            *(ushort8*)&lds_k[cur ^ 1][r1 * 72 + c81]  = kreg[1];
            *(ushort8*)&lds_vt[cur ^ 1][r0 * 72 + c80] = vreg[0];
            *(ushort8*)&lds_vt[cur ^ 1][r1 * 72 + c81] = vreg[1];
            __syncthreads();
        }
    }

    // epilogue: lacc C-layout rows == o rows -> direct divide, store
#pragma unroll
    for (int mt = 0; mt < 2; mt++)
#pragma unroll
        for (int r = 0; r < 4; r++) {
            float inv = 1.0f / lacc[mt][r];
            int gq = q0 + wave * 32 + mt * 16 + quad * 4 + r;
            size_t rowoff = base_bh + (size_t)gq * D;
#pragma unroll
            for (int d = 0; d < 4; d++)
                Xo[rowoff + d * 16 + lane15] = f2bf(o[mt][d][r] * inv);
        }
}

extern "C" void kernel_launch(void* const* d_in, const int* in_sizes, int n_in,
                              void* d_out, int out_size, void* d_ws, size_t ws_size,
                              hipStream_t stream) {
    const float* q  = (const float*)d_in[0];
    const float* k  = (const float*)d_in[1];
    const float* v  = (const float*)d_in[2];
    const float* wq = (const float*)d_in[3];
    const float* bq = (const float*)d_in[4];
    const float* wk = (const float*)d_in[5];
    const float* bk = (const float*)d_in[6];
    const float* wv = (const float*)d_in[7];
    const float* bv = (const float*)d_in[8];
    const float* wo = (const float*)d_in[9];
    const float* bo = (const float*)d_in[10];
    float* out = (float*)d_out;

    const int M = 8192, N = 768, K = 768;
    const size_t BIG = (size_t)M * N;        // 6291456
    const size_t WSZ = (size_t)N * K;        // 589824

    unsigned short* ws = (unsigned short*)d_ws;
    unsigned short* qb  = ws;                 // [8192][768]
    unsigned short* kb  = qb + BIG;
    unsigned short* vt  = kb + BIG;           // [768][8192] (V^T)
    unsigned short* xq  = vt + BIG;           // converted inputs
    unsigned short* xk  = xq + BIG;
    unsigned short* xv  = xk + BIG;
    unsigned short* wqb = xv + BIG;           // converted weights
    unsigned short* wkb = wqb + WSZ;
    unsigned short* wvb = wkb + WSZ;
    unsigned short* wob = wvb + WSZ;
    unsigned short* xb  = xq;                 // attn output reuses xq (dead)

    const size_t need = (6 * BIG + 4 * WSZ) * sizeof(unsigned short);

    if (ws_size >= need) {
        // pre-convert inputs + weights to bf16 (grid-stride)
        cvt_bf16<<<dim3(512, 3), 256, 0, stream>>>(
            q, xq, k, xk, v, xv, v, xv, (int)BIG);
        cvt_bf16<<<dim3(96, 4), 256, 0, stream>>>(
            wq, wqb, wk, wkb, wv, wvb, wo, wob, (int)WSZ);

        dim3 g1(M / 128, N / 96, 3);          // 64 x 8 x 3 = 1536 blocks
        gemm_bt<3, unsigned short, unsigned short, unsigned short>
            <<<g1, 256, 0, stream>>>(xq, wqb, bq, qb,
                                     xk, wkb, bk, kb,
                                     xv, wvb, bv, vt, M, N, K, 1, SCL);

        attn<<<dim3(4096 / 128, 2 * 12), 256, 0, stream>>>(qb, kb, vt, xb);

        dim3 g2(M / 128, N / 64, 1);          // 64 x 12 = 768 blocks
        gemm_bt<2, unsigned short, unsigned short, float>
            <<<g2, 256, 0, stream>>>(xb, wob, bo, out,
                                     xb, wob, bo, out,
                                     xb, wob, bo, out, M, N, K, 0, 1.0f);
    } else {
        // fallback: fp32 staging + V^T write + attn
        unsigned short* fqb = ws;
        unsigned short* fkb = fqb + BIG;
        unsigned short* fvt = fkb + BIG;
        unsigned short* fxb = fvt + BIG;

        dim3 g1(M / 128, N / 96, 3);
        gemm_bt<3, float, float, unsigned short>
            <<<g1, 256, 0, stream>>>(q, wq, bq, fqb,
                                     k, wk, bk, fkb,
                                     v, wv, bv, fvt, M, N, K, 1, SCL);

        attn<<<dim3(4096 / 128, 2 * 12), 256, 0, stream>>>(fqb, fkb, fvt, fxb);

        dim3 g2(M / 128, N / 64, 1);
        gemm_bt<2, unsigned short, float, float>
            <<<g2, 256, 0, stream>>>(fxb, wo, bo, out,
                                     fxb, wo, bo, out,
                                     fxb, wo, bo, out, M, N, K, 0, 1.0f);
    }
}